// Round 5
// baseline (232.158 us; speedup 1.0000x reference)
//
#include <hip/hip_runtime.h>

#define S_VOX (128*128*128)   // spatial voxels per (b,n) plane = 2097152
#define QV (S_VOX/4)          // float4 groups per plane = 524288
#define CHUNKS 512
#define CHUNK_Q (QV / CHUNKS) // 1024 q-groups per block per stream
#define EPSF 1e-10f
#define SMOOTHF 1e-5f

// ws layout (floats): [0] ce_sum, [1+plane] inter, [17+plane] ground, [33+plane] pred_o
// where plane = b*8+n
#define NACC 49

__device__ __forceinline__ float wave_reduce(float v) {
#pragma unroll
    for (int off = 32; off > 0; off >>= 1)
        v += __shfl_down(v, off, 64);
    return v;
}

// R5 = R4's demand geometry x R3's concurrency codegen.
// Evidence: R3 (3 streams, 62% occ) sustained 4.4 TB/s of demand but wasted
// 2.7x bytes on target re-reads; R4 (lean 192 MB demand) collapsed to 26% occ
// (launch_bounds(256,3) + 24-load burst -> compiler re-interleaved at 68 VGPR)
// and only 2.3 TB/s. So: keep the 4-planes-per-block mapping (pred 128 MB +
// tgt 64 MB total; the 4 consecutive blocks j=0..3 of a chunk share its two
// target chunks -> L2 temporal locality), but use the simple per-iteration
// load->consume loop with no min-waves bound so occupancy returns to R3
// levels and TLP (6 in-flight loads/wave x ~20 waves/CU) hides latency.
// CE decomposition: ce = sum_{b,b',vox} log(pred[b, t[b',vox], vox] + EPS);
// plane (b,n) contributes c_n = (t0==n)+(t1==n) copies of log(pred[b,n]+EPS);
// c_n is batch-independent -> fold: c_n * log((p0n+E)*(p1n+E)).
__global__ __launch_bounds__(256) void dice_main(const float* __restrict__ pred,
                                                 const int* __restrict__ tgt,
                                                 float* __restrict__ ws) {
    const int chunk = blockIdx.x >> 2;        // 0..511
    const int n0    = (blockIdx.x & 3) * 2;   // n-pair: {n0, n0+1}

    const size_t cb = (size_t)chunk * CHUNK_Q;
    const float4* p00 = (const float4*)pred + (size_t)(n0    ) * QV + cb; // b0,n0
    const float4* p01 = (const float4*)pred + (size_t)(n0 + 1) * QV + cb; // b0,n0+1
    const float4* p10 = (const float4*)pred + (size_t)(n0 + 8) * QV + cb; // b1,n0
    const float4* p11 = (const float4*)pred + (size_t)(n0 + 9) * QV + cb; // b1,n0+1
    const int4*   t0p = (const int4*)tgt + cb;              // batch-0 target
    const int4*   t1p = (const int4*)tgt + (size_t)QV + cb; // batch-1 target

    float ce = 0.f;
    float inter[4] = {0.f, 0.f, 0.f, 0.f};
    float po[4]    = {0.f, 0.f, 0.f, 0.f};
    int   gc[4]    = {0, 0, 0, 0};
    // local plane l: b = l>>1, n = n0+(l&1); global plane = (l>>1)*8 + n0 + (l&1)

    for (int k = 0; k < 4; ++k) {
        const int i = threadIdx.x + k * 256;
        const float4 q0 = p00[i];
        const float4 q1 = p01[i];
        const float4 q2 = p10[i];
        const float4 q3 = p11[i];
        const int4   ta = t0p[i];
        const int4   tb = t1p[i];

#define VOXEL(pa, pb, pc, pd, u, v)                                     \
        {                                                               \
            const int ua = ((u) == n0);                                 \
            const int ub = ((u) == n0 + 1);                             \
            const int va = ((v) == n0);                                 \
            const int vb = ((v) == n0 + 1);                             \
            inter[0] += ua ? (pa) : 0.f;  gc[0] += ua;                  \
            inter[1] += ub ? (pb) : 0.f;  gc[1] += ub;                  \
            inter[2] += va ? (pc) : 0.f;  gc[2] += va;                  \
            inter[3] += vb ? (pd) : 0.f;  gc[3] += vb;                  \
            ce += (float)(ua + va) * __logf(((pa) + EPSF) * ((pc) + EPSF)); \
            ce += (float)(ub + vb) * __logf(((pb) + EPSF) * ((pd) + EPSF)); \
            po[0] += (pa); po[1] += (pb); po[2] += (pc); po[3] += (pd); \
        }
        VOXEL(q0.x, q1.x, q2.x, q3.x, ta.x, tb.x)
        VOXEL(q0.y, q1.y, q2.y, q3.y, ta.y, tb.y)
        VOXEL(q0.z, q1.z, q2.z, q3.z, ta.z, tb.z)
        VOXEL(q0.w, q1.w, q2.w, q3.w, ta.w, tb.w)
#undef VOXEL
    }

    // ---- block reduction: 13 scalars ----
    __shared__ float red[4][13];
    const int lane = threadIdx.x & 63;
    const int wave = threadIdx.x >> 6;
    float acc[13];
    acc[0] = ce;
#pragma unroll
    for (int l = 0; l < 4; l++) {
        acc[1 + l] = inter[l];
        acc[5 + l] = (float)gc[l];
        acc[9 + l] = po[l];
    }
#pragma unroll
    for (int i = 0; i < 13; i++) {
        float v = wave_reduce(acc[i]);
        if (lane == 0) red[wave][i] = v;
    }
    __syncthreads();
    if (threadIdx.x < 13) {
        const int i = threadIdx.x;
        const float s = red[0][i] + red[1][i] + red[2][i] + red[3][i];
        int dst;
        if (i == 0) {
            dst = 0;                                        // ce
        } else {
            const int l = (i - 1) & 3;                      // local plane
            const int plane = ((l >> 1) * 8) + n0 + (l & 1);
            if (i <= 4)      dst = 1  + plane;              // inter
            else if (i <= 8) dst = 17 + plane;              // ground
            else             dst = 33 + plane;              // pred_o
        }
        atomicAdd(&ws[dst], s);
    }
}

__global__ void dice_finalize(const float* __restrict__ ws, float* __restrict__ out) {
    const int i = threadIdx.x;
    float term = 0.f;
    if (i < 16) {
        float inter = ws[1 + i];
        float g     = ws[17 + i];
        float p     = ws[33 + i];
        term = 1.0f - (2.0f * inter + SMOOTHF) / (g + p + SMOOTHF);
    }
    term = wave_reduce(term);
    if (i == 0) {
        // celoss = -ce_sum / (B*B*S)  with B=2
        float celoss = -ws[0] / (4.0f * (float)S_VOX);
        out[0] = celoss + term * (1.0f / 16.0f);
    }
}

extern "C" void kernel_launch(void* const* d_in, const int* in_sizes, int n_in,
                              void* d_out, int out_size, void* d_ws, size_t ws_size,
                              hipStream_t stream) {
    const float* pred = (const float*)d_in[0];
    const int*   tgt  = (const int*)d_in[1];
    float* ws  = (float*)d_ws;
    float* out = (float*)d_out;

    hipMemsetAsync(ws, 0, NACC * sizeof(float), stream);
    // 2048 blocks = 512 chunks x 4 n-pairs; 256 threads; 4 simple iters/thread
    dice_main<<<CHUNKS * 4, 256, 0, stream>>>(pred, tgt, ws);
    dice_finalize<<<1, 64, 0, stream>>>(ws, out);
}

// Round 6
// 210.970 us; speedup vs baseline: 1.1004x; 1.1004x over previous
//
#include <hip/hip_runtime.h>

#define S_VOX (128*128*128)   // spatial voxels per (b,n) plane = 2097152
#define QV (S_VOX/4)          // float4 groups per plane = 524288
#define CHUNK_Q 256           // q-groups per chunk = one float4 per thread per stream
#define CHUNKS (QV / CHUNK_Q) // 2048 chunks
#define EPSF 1e-10f
#define SMOOTHF 1e-5f

// ws: 8 replicas (one per XCD), stride 64 floats.
// Within a replica: [0] ce_sum, [1+plane] inter, [17+plane] ground, [33+plane] pred_o
#define NREP 8
#define REP_STRIDE 64

__device__ __forceinline__ float wave_reduce(float v) {
#pragma unroll
    for (int off = 32; off > 0; off >>= 1)
        v += __shfl_down(v, off, 64);
    return v;
}

// R6: identical math to R5 (4 planes/block, 192 MB demand), new dispatch
// geometry. Two fixes motivated by R5's counters (84us, 62% occ, VGPR 32):
// (1) Tail: 2048 coarse blocks -> ~1/3 of dispatch is ramp/drain. Now 8192
//     one-shot blocks (1 load-batch/thread, no loop): 4x finer drain quanta,
//     shortest possible dependent chain.
// (2) XCD swizzle: workgroup->XCD round-robins on id%8, so R5's "consecutive
//     sharer blocks" of a target chunk landed on 4 DIFFERENT L2s (no reuse).
//     Now chunk = xcd + 8*k: the 4 sharers of a chunk have ids spaced exactly
//     8 apart (same XCD, dispatched within a 32-id window) -> target chunk is
//     filled into ONE L2 and reused 3x; lower average latency frees MSHRs
//     faster (throughput = in-flight-lines/latency).
// Atomics: 8192 blocks x 13 adds would serialize on 49 addresses -> 8-way
// replicated accumulators (replica = xcd), summed in finalize.
// CE decomposition: ce = sum_{b,b',vox} log(pred[b, t[b',vox], vox] + EPS);
// plane (b,n) gets c_n = (t0==n)+(t1==n) copies of log(pred[b,n]+EPS); c_n is
// batch-independent -> fold: c_n * log((p0n+E)*(p1n+E)).
__global__ __launch_bounds__(256) void dice_main(const float* __restrict__ pred,
                                                 const int* __restrict__ tgt,
                                                 float* __restrict__ ws) {
    const int xcd = blockIdx.x & 7;
    const int s   = blockIdx.x >> 3;
    const int chunk = xcd + 8 * (s >> 2);   // 0..2047, sharers same-XCD
    const int n0    = (s & 3) * 2;          // n-pair {n0, n0+1}

    const size_t cb = (size_t)chunk * CHUNK_Q;
    const float4* p00 = (const float4*)pred + (size_t)(n0    ) * QV + cb; // b0,n0
    const float4* p01 = (const float4*)pred + (size_t)(n0 + 1) * QV + cb; // b0,n0+1
    const float4* p10 = (const float4*)pred + (size_t)(n0 + 8) * QV + cb; // b1,n0
    const float4* p11 = (const float4*)pred + (size_t)(n0 + 9) * QV + cb; // b1,n0+1
    const int4*   t0p = (const int4*)tgt + cb;              // batch-0 target
    const int4*   t1p = (const int4*)tgt + (size_t)QV + cb; // batch-1 target

    const int i = threadIdx.x;   // CHUNK_Q == blockDim.x: one float4 per stream
    const float4 q0 = p00[i];
    const float4 q1 = p01[i];
    const float4 q2 = p10[i];
    const float4 q3 = p11[i];
    const int4   ta = t0p[i];
    const int4   tb = t1p[i];

    float ce = 0.f;
    float inter[4] = {0.f, 0.f, 0.f, 0.f};
    float po[4];
    int   gc[4] = {0, 0, 0, 0};
    po[0] = (q0.x + q0.y) + (q0.z + q0.w);
    po[1] = (q1.x + q1.y) + (q1.z + q1.w);
    po[2] = (q2.x + q2.y) + (q2.z + q2.w);
    po[3] = (q3.x + q3.y) + (q3.z + q3.w);

#define VOXEL(pa, pb, pc, pd, u, v)                                     \
    {                                                                   \
        const int ua = ((u) == n0);                                     \
        const int ub = ((u) == n0 + 1);                                 \
        const int va = ((v) == n0);                                     \
        const int vb = ((v) == n0 + 1);                                 \
        inter[0] += ua ? (pa) : 0.f;  gc[0] += ua;                      \
        inter[1] += ub ? (pb) : 0.f;  gc[1] += ub;                      \
        inter[2] += va ? (pc) : 0.f;  gc[2] += va;                      \
        inter[3] += vb ? (pd) : 0.f;  gc[3] += vb;                      \
        ce += (float)(ua + va) * __logf(((pa) + EPSF) * ((pc) + EPSF)); \
        ce += (float)(ub + vb) * __logf(((pb) + EPSF) * ((pd) + EPSF)); \
    }
    VOXEL(q0.x, q1.x, q2.x, q3.x, ta.x, tb.x)
    VOXEL(q0.y, q1.y, q2.y, q3.y, ta.y, tb.y)
    VOXEL(q0.z, q1.z, q2.z, q3.z, ta.z, tb.z)
    VOXEL(q0.w, q1.w, q2.w, q3.w, ta.w, tb.w)
#undef VOXEL

    // ---- block reduction: 13 scalars ----
    __shared__ float red[4][13];
    const int lane = threadIdx.x & 63;
    const int wave = threadIdx.x >> 6;
    float acc[13];
    acc[0] = ce;
#pragma unroll
    for (int l = 0; l < 4; l++) {
        acc[1 + l] = inter[l];
        acc[5 + l] = (float)gc[l];
        acc[9 + l] = po[l];
    }
#pragma unroll
    for (int k = 0; k < 13; k++) {
        float v = wave_reduce(acc[k]);
        if (lane == 0) red[wave][k] = v;
    }
    __syncthreads();
    if (threadIdx.x < 13) {
        const int k = threadIdx.x;
        const float sum = red[0][k] + red[1][k] + red[2][k] + red[3][k];
        int dst;
        if (k == 0) {
            dst = 0;                                        // ce
        } else {
            const int l = (k - 1) & 3;                      // local plane
            const int plane = ((l >> 1) * 8) + n0 + (l & 1);
            if (k <= 4)      dst = 1  + plane;              // inter
            else if (k <= 8) dst = 17 + plane;              // ground
            else             dst = 33 + plane;              // pred_o
        }
        atomicAdd(&ws[xcd * REP_STRIDE + dst], sum);
    }
}

__global__ void dice_finalize(const float* __restrict__ ws, float* __restrict__ out) {
    const int i = threadIdx.x;
    float term = 0.f;
    if (i < 16) {
        float inter = 0.f, g = 0.f, p = 0.f;
#pragma unroll
        for (int r = 0; r < NREP; r++) {
            inter += ws[r * REP_STRIDE + 1  + i];
            g     += ws[r * REP_STRIDE + 17 + i];
            p     += ws[r * REP_STRIDE + 33 + i];
        }
        term = 1.0f - (2.0f * inter + SMOOTHF) / (g + p + SMOOTHF);
    }
    term = wave_reduce(term);
    if (i == 0) {
        float ce = 0.f;
#pragma unroll
        for (int r = 0; r < NREP; r++) ce += ws[r * REP_STRIDE];
        // celoss = -ce_sum / (B*B*S)  with B=2
        float celoss = -ce / (4.0f * (float)S_VOX);
        out[0] = celoss + term * (1.0f / 16.0f);
    }
}

extern "C" void kernel_launch(void* const* d_in, const int* in_sizes, int n_in,
                              void* d_out, int out_size, void* d_ws, size_t ws_size,
                              hipStream_t stream) {
    const float* pred = (const float*)d_in[0];
    const int*   tgt  = (const int*)d_in[1];
    float* ws  = (float*)d_ws;
    float* out = (float*)d_out;

    hipMemsetAsync(ws, 0, NREP * REP_STRIDE * sizeof(float), stream);
    // 8192 blocks = 2048 chunks x 4 n-pairs, XCD-bijective mapping, 1 iter/thread
    dice_main<<<CHUNKS * 4, 256, 0, stream>>>(pred, tgt, ws);
    dice_finalize<<<1, 64, 0, stream>>>(ws, out);
}